// Round 10
// baseline (360.828 us; speedup 1.0000x reference)
//
#include <hip/hip_runtime.h>
#include <cstdint>

#define EPSV 1e-5f

typedef __bf16 bf16x8 __attribute__((ext_vector_type(8)));
typedef __bf16 bf16x2 __attribute__((ext_vector_type(2)));
typedef float  f32x4  __attribute__((ext_vector_type(4)));
typedef unsigned long long u64;
typedef unsigned int u32;

#define NSB  512   // scatter/histogram blocks
#define BCAP 6144  // max edges per 256-node bucket (mean 4096, ~32 sigma guard)

// fp8 e4m3 (OCP) helpers — HW converts on gfx950.
__device__ __forceinline__ unsigned char f32_to_fp8(float x) {
    const int p = __builtin_amdgcn_cvt_pk_fp8_f32(x, x, 0, false);
    return (unsigned char)(p & 0xFF);
}

// ---------------------------------------------- bucket histogram (LDS) ----
__global__ __launch_bounds__(256) void k_bh(const int* __restrict__ eic,
                                            u32* __restrict__ bhT,
                                            int E, int CH, int NBK) {
    __shared__ int h[400];
    for (int i = threadIdx.x; i < NBK; i += 256) h[i] = 0;
    __syncthreads();
    const int lo = blockIdx.x * CH;
    const int hi = min(E, lo + CH);
    for (int e = lo + threadIdx.x; e < hi; e += 256)
        atomicAdd(&h[eic[e] >> 8], 1);
    __syncthreads();
    for (int b = threadIdx.x; b < NBK; b += 256)
        bhT[b * NSB + blockIdx.x] = (u32)h[b];
}

// --------------- scan: bucket ranges barr[] + per-(bucket,blk) bases ------
__global__ __launch_bounds__(256) void k_bscan(const u32* __restrict__ bhT,
                                               u32* __restrict__ baseT,
                                               int* __restrict__ barr, int NBK) {
    __shared__ int tot[400];
    for (int b = threadIdx.x; b < NBK; b += 256) {
        const uint4* p = (const uint4*)(bhT + b * NSB);
        int s = 0;
        for (int j = 0; j < NSB / 4; ++j) {
            const uint4 v = p[j];
            s += (int)(v.x + v.y + v.z + v.w);
        }
        tot[b] = s;
    }
    __syncthreads();
    if (threadIdx.x == 0) {
        int run = 0;
        for (int b = 0; b < NBK; ++b) {
            const int t = tot[b];
            barr[b] = run;
            tot[b] = run;
            run += t;
        }
        barr[NBK] = run;
    }
    __syncthreads();
    for (int b = threadIdx.x; b < NBK; b += 256) {
        u32 run = (u32)tot[b];
        const u32* p = bhT + b * NSB;
        u32* q = baseT + b * NSB;
        for (int j = 0; j < NSB; ++j) {
            const u32 t = p[j];
            q[j] = run;
            run += t;
        }
    }
}

// ------------------- scatter edges into buckets (plain stores, LDS rank) --
// pack: (c&255)<<33 | r<<16 | w16   (r<2^17, w16 = round(w*65535))
__global__ __launch_bounds__(256) void k_bscat(const int* __restrict__ ei,
                                               const float* __restrict__ ew,
                                               const u32* __restrict__ baseT,
                                               u64* __restrict__ buck,
                                               int E, int CH, int NBK) {
    __shared__ u32 base[400];
    __shared__ u32 cur[400];
    for (int i = threadIdx.x; i < NBK; i += 256) {
        base[i] = baseT[i * NSB + blockIdx.x];
        cur[i] = 0;
    }
    __syncthreads();
    const int lo = blockIdx.x * CH;
    const int hi = min(E, lo + CH);
    for (int e = lo + threadIdx.x; e < hi; e += 256) {
        const int c = ei[E + e];
        const int r = ei[e];
        const int b = c >> 8;
        const u32 rk = atomicAdd(&cur[b], 1u);
        const u32 w16 = (u32)(ew[e] * 65535.0f + 0.5f);
        buck[base[b] + rk] = ((u64)(c & 255) << 33) | ((u64)r << 16) | (u64)w16;
    }
}

// ------ per-bucket: counts, deg, node-sort; emits cnt/off/dinv + srt ------
__global__ __launch_bounds__(256) void k_bucket(const u64* __restrict__ buck,
                                                const int* __restrict__ barr,
                                                u64* __restrict__ srt,
                                                int* __restrict__ cnt,
                                                int* __restrict__ off,
                                                float* __restrict__ dinv, int N) {
    __shared__ u64 arr[BCAP];
    __shared__ int lc[256];
    __shared__ float ldeg[256];
    __shared__ int loff[256];
    __shared__ int wsum[4];
    const int b = blockIdx.x;
    const int e0 = barr[b];
    const int nb = min(barr[b + 1] - e0, BCAP);

    lc[threadIdx.x] = 0;
    ldeg[threadIdx.x] = 0.f;
    __syncthreads();

    for (int i = threadIdx.x; i < nb; i += 256) {
        const u64 v = buck[e0 + i];
        arr[i] = v;
        const int cl = (int)(v >> 33) & 255;
        atomicAdd(&lc[cl], 1);
        atomicAdd(&ldeg[cl], (float)(u32)(v & 0xFFFF) * (1.0f / 65535.0f));
    }
    __syncthreads();

    // exclusive scan of lc -> loff
    const int lane = threadIdx.x & 63, w = threadIdx.x >> 6;
    const int vv = lc[threadIdx.x];
    int s = vv;
#pragma unroll
    for (int o = 1; o < 64; o <<= 1) {
        const int t = __shfl_up(s, o);
        if (lane >= o) s += t;
    }
    if (lane == 63) wsum[w] = s;
    __syncthreads();
    int add = 0;
    for (int k = 0; k < w; ++k) add += wsum[k];
    loff[threadIdx.x] = add + s - vv;
    __syncthreads();

    const int c = b * 256 + threadIdx.x;
    if (c < N) {
        cnt[c] = vv;
        off[c] = e0 + loff[threadIdx.x];
        dinv[c] = rsqrtf(1.0f + ldeg[threadIdx.x]);
    }

    __syncthreads();
    lc[threadIdx.x] = 0;
    __syncthreads();
    for (int i = threadIdx.x; i < nb; i += 256) {
        const u64 v = arr[i];
        const int cl = (int)(v >> 33) & 255;
        const int rk = atomicAdd(&lc[cl], 1);
        srt[e0 + loff[cl] + rk] =
            ((u64)(b * 256 + cl) << 33) | (v & 0x1FFFFFFFFull);
    }
}

// ------------------------- norms: ern[p] = (r, dinv[r]*w*dinv[c]) ---------
__global__ __launch_bounds__(256) void k_norm(const u64* __restrict__ srt,
                                              const float* __restrict__ dinv,
                                              float2* __restrict__ ern, int E) {
    const int p = blockIdx.x * 256 + threadIdx.x;
    if (p >= E) return;
    const u64 v = srt[p];
    const int c = (int)(v >> 33);
    const int r = (int)((v >> 16) & 0x1FFFF);
    const float w = (float)(u32)(v & 0xFFFF) * (1.0f / 65535.0f);
    ern[p] = make_float2(__int_as_float(r), dinv[r] * w * dinv[c]);
}

// ----------------------------------------------------- W transpose+cvt ----
// Blob layout: WtB[k/8][c][8] bf16.
__global__ __launch_bounds__(256) void k_wcvt(const float* __restrict__ W1,
                                              __bf16* __restrict__ Wt1,
                                              const float* __restrict__ W2,
                                              __bf16* __restrict__ Wt2) {
    const int idx = blockIdx.x * 256 + threadIdx.x;
    if (idx < 256 * 128) {                       // K=256, NOUT=128
        const int k = idx >> 7, c = idx & 127;
        Wt1[(((k >> 3) << 7) + c) * 8 + (k & 7)] = (__bf16)W1[idx];
    } else if (idx < 256 * 128 + 128 * 64) {     // K=128, NOUT=64
        const int j = idx - 256 * 128;
        const int k = j >> 6, c = j & 63;
        Wt2[(((k >> 3) << 6) + c) * 8 + (k & 7)] = (__bf16)W2[j];
    }
}

// ----------------------------------------------------------- MFMA GEMM ----
template <int K, int NOUT, bool ABF16>
__device__ __forceinline__ void mm_body(int bid, int tid, const void* __restrict__ Xv,
                                        const __bf16* __restrict__ WtB,
                                        unsigned char* __restrict__ H, int N) {
    constexpr int NCB = NOUT / 16;
    constexpr int NKB = K / 32;
    const int w = tid >> 6, l = tid & 63;
    const int r0 = l & 15, kq = l >> 4;
    const long tb0 = (long)bid * 128 + w * 32;
    const long ar0 = (tb0 + r0) < N ? (tb0 + r0) : (long)N - 1;
    const long ar1 = (tb0 + 16 + r0) < N ? (tb0 + 16 + r0) : (long)N - 1;

    f32x4 acc[2][NCB];
#pragma unroll
    for (int rf = 0; rf < 2; ++rf)
#pragma unroll
        for (int cb = 0; cb < NCB; ++cb) acc[rf][cb] = (f32x4){0.f, 0.f, 0.f, 0.f};

#define LDA(kb, a0, a1)                                                          \
    {                                                                            \
        const int koff = (kb) * 32 + kq * 8;                                     \
        if constexpr (ABF16) {                                                   \
            a0 = *reinterpret_cast<const bf16x8*>((const __bf16*)Xv + ar0 * K + koff); \
            a1 = *reinterpret_cast<const bf16x8*>((const __bf16*)Xv + ar1 * K + koff); \
        } else {                                                                 \
            const float* p0 = (const float*)Xv + ar0 * K + koff;                 \
            const float* p1 = (const float*)Xv + ar1 * K + koff;                 \
            const float4 u0 = *reinterpret_cast<const float4*>(p0);              \
            const float4 u1 = *reinterpret_cast<const float4*>(p0 + 4);          \
            const float4 u2 = *reinterpret_cast<const float4*>(p1);              \
            const float4 u3 = *reinterpret_cast<const float4*>(p1 + 4);          \
            a0[0] = (__bf16)u0.x; a0[1] = (__bf16)u0.y; a0[2] = (__bf16)u0.z;    \
            a0[3] = (__bf16)u0.w; a0[4] = (__bf16)u1.x; a0[5] = (__bf16)u1.y;    \
            a0[6] = (__bf16)u1.z; a0[7] = (__bf16)u1.w;                          \
            a1[0] = (__bf16)u2.x; a1[1] = (__bf16)u2.y; a1[2] = (__bf16)u2.z;    \
            a1[3] = (__bf16)u2.w; a1[4] = (__bf16)u3.x; a1[5] = (__bf16)u3.y;    \
            a1[6] = (__bf16)u3.z; a1[7] = (__bf16)u3.w;                          \
        }                                                                        \
    }

#define LDB(kb, b)                                                               \
    {                                                                            \
        const __bf16* bp = WtB + (long)(((kb) * 4 + kq) * NOUT + r0) * 8;        \
        _Pragma("unroll") for (int cb = 0; cb < NCB; ++cb)                       \
            b[cb] = *reinterpret_cast<const bf16x8*>(bp + cb * 128);             \
    }

    bf16x8 aC0, aC1, aN0, aN1;
    bf16x8 bC[NCB], bN[NCB];
    LDA(0, aC0, aC1);
    LDB(0, bC);
#pragma unroll
    for (int kb = 0; kb < NKB; ++kb) {
        if (kb + 1 < NKB) {
            LDA(kb + 1, aN0, aN1);
            LDB(kb + 1, bN);
        }
#pragma unroll
        for (int cb = 0; cb < NCB; ++cb) {
            acc[0][cb] = __builtin_amdgcn_mfma_f32_16x16x32_bf16(aC0, bC[cb], acc[0][cb], 0, 0, 0);
            acc[1][cb] = __builtin_amdgcn_mfma_f32_16x16x32_bf16(aC1, bC[cb], acc[1][cb], 0, 0, 0);
        }
        aC0 = aN0; aC1 = aN1;
#pragma unroll
        for (int cb = 0; cb < NCB; ++cb) bC[cb] = bN[cb];
    }
#undef LDA
#undef LDB

    const int orow = kq * 4;
#pragma unroll
    for (int rf = 0; rf < 2; ++rf)
#pragma unroll
        for (int cb = 0; cb < NCB; ++cb)
#pragma unroll
            for (int r = 0; r < 4; ++r) {
                const long gr = tb0 + rf * 16 + orow + r;
                if (gr < N) H[gr * NOUT + cb * 16 + r0] = f32_to_fp8(acc[rf][cb][r]);
            }
}

__global__ __launch_bounds__(256) void k_mm1(const float* __restrict__ X,
                                             const __bf16* __restrict__ Wt1,
                                             unsigned char* __restrict__ H, int N) {
    mm_body<256, 128, false>(blockIdx.x, threadIdx.x, X, Wt1, H, N);
}

__global__ __launch_bounds__(256) void k_mm2(const __bf16* __restrict__ X,
                                             const __bf16* __restrict__ Wt2,
                                             unsigned char* __restrict__ H, int N) {
    mm_body<128, 64, true>(blockIdx.x, threadIdx.x, X, Wt2, H, N);
}

// --------------------------------- gather + bias + ReLU + LayerNorm -------
__global__ __launch_bounds__(256) void k_gat128(const unsigned char* __restrict__ H,
                                                const int* __restrict__ off,
                                                const int* __restrict__ cnt,
                                                const float2* __restrict__ ern,
                                                const float* __restrict__ dinv,
                                                const float* __restrict__ bias,
                                                const float* __restrict__ gm,
                                                const float* __restrict__ bt,
                                                __bf16* __restrict__ Out, int N) {
    const long wv = ((long)blockIdx.x * 256 + threadIdx.x) >> 6;
    const int lane = threadIdx.x & 63;
    if (wv >= N) return;
    const int s = off[wv];
    const int n = cnt[wv];
    const float d = dinv[wv];
    const unsigned short* Hp = reinterpret_cast<const unsigned short*>(H);

    const unsigned int h0 = Hp[wv * 64 + lane];
    float ax = __builtin_amdgcn_cvt_f32_fp8(h0, 0) * d * d;
    float ay = __builtin_amdgcn_cvt_f32_fp8(h0, 1) * d * d;

    int e = 0;
    for (; e + 8 <= n; e += 8) {
        float2 q[8];
#pragma unroll
        for (int j = 0; j < 8; ++j) q[j] = ern[s + e + j];
        unsigned int u[8];
#pragma unroll
        for (int j = 0; j < 8; ++j)
            u[j] = Hp[(long)__float_as_int(q[j].x) * 64 + lane];
#pragma unroll
        for (int j = 0; j < 8; ++j) {
            ax = fmaf(q[j].y, __builtin_amdgcn_cvt_f32_fp8(u[j], 0), ax);
            ay = fmaf(q[j].y, __builtin_amdgcn_cvt_f32_fp8(u[j], 1), ay);
        }
    }
    for (; e < n; ++e) {
        const float2 q = ern[s + e];
        const unsigned int u = Hp[(long)__float_as_int(q.x) * 64 + lane];
        ax = fmaf(q.y, __builtin_amdgcn_cvt_f32_fp8(u, 0), ax);
        ay = fmaf(q.y, __builtin_amdgcn_cvt_f32_fp8(u, 1), ay);
    }

    const float ux = fmaxf(ax + bias[2 * lane], 0.f);
    const float uy = fmaxf(ay + bias[2 * lane + 1], 0.f);
    float s1 = ux + uy, s2 = ux * ux + uy * uy;
#pragma unroll
    for (int o = 32; o >= 1; o >>= 1) {
        s1 += __shfl_xor(s1, o);
        s2 += __shfl_xor(s2, o);
    }
    const float mu = s1 * (1.f / 128.f);
    const float var = s2 * (1.f / 128.f) - mu * mu;
    const float rs = rsqrtf(var + EPSV);
    bf16x2 ob;
    ob[0] = (__bf16)((ux - mu) * rs * gm[2 * lane] + bt[2 * lane]);
    ob[1] = (__bf16)((uy - mu) * rs * gm[2 * lane + 1] + bt[2 * lane + 1]);
    reinterpret_cast<bf16x2*>(Out)[wv * 64 + lane] = ob;
}

__global__ __launch_bounds__(256) void k_gat64(const unsigned char* __restrict__ H,
                                               const int* __restrict__ off,
                                               const int* __restrict__ cnt,
                                               const float2* __restrict__ ern,
                                               const float* __restrict__ dinv,
                                               const float* __restrict__ bias,
                                               const float* __restrict__ gm,
                                               const float* __restrict__ bt,
                                               __bf16* __restrict__ Out, int N) {
    const long wv = ((long)blockIdx.x * 256 + threadIdx.x) >> 6;
    const int lane = threadIdx.x & 63;
    if (wv >= N) return;
    const int s = off[wv];
    const int n = cnt[wv];
    const float d = dinv[wv];

    float acc = __builtin_amdgcn_cvt_f32_fp8((unsigned int)H[wv * 64 + lane], 0) * d * d;
    int e = 0;
    for (; e + 8 <= n; e += 8) {
        float2 q[8];
#pragma unroll
        for (int j = 0; j < 8; ++j) q[j] = ern[s + e + j];
        unsigned int u[8];
#pragma unroll
        for (int j = 0; j < 8; ++j)
            u[j] = H[(long)__float_as_int(q[j].x) * 64 + lane];
#pragma unroll
        for (int j = 0; j < 8; ++j)
            acc = fmaf(q[j].y, __builtin_amdgcn_cvt_f32_fp8(u[j], 0), acc);
    }
    for (; e < n; ++e) {
        const float2 q = ern[s + e];
        const unsigned int u = H[(long)__float_as_int(q.x) * 64 + lane];
        acc = fmaf(q.y, __builtin_amdgcn_cvt_f32_fp8(u, 0), acc);
    }

    const float u = fmaxf(acc + bias[lane], 0.f);
    float s1 = u, s2 = u * u;
#pragma unroll
    for (int o = 32; o >= 1; o >>= 1) {
        s1 += __shfl_xor(s1, o);
        s2 += __shfl_xor(s2, o);
    }
    const float mu = s1 * (1.f / 64.f);
    const float var = s2 * (1.f / 64.f) - mu * mu;
    const float rs = rsqrtf(var + EPSV);
    Out[wv * 64 + lane] = (__bf16)((u - mu) * rs * gm[lane] + bt[lane]);
}

// ---------------------------------------------------------------- pool ----
__global__ __launch_bounds__(256) void k_pool(const __bf16* __restrict__ C,
                                              const int* __restrict__ batch,
                                              float* __restrict__ pool,
                                              int N, int chunk) {
    const int wg = blockIdx.x * 4 + (threadIdx.x >> 6);
    const int lane = threadIdx.x & 63;
    long i = (long)wg * chunk;
    const long end = (i + chunk < (long)N) ? i + chunk : (long)N;
    if (i >= end) return;

    int cur = batch[i];
    float acc = 0.f;
    int cn = 0;
    while (i < end) {
        if (i + 8 <= end && batch[i + 7] == cur) {
            float v[8];
#pragma unroll
            for (int j = 0; j < 8; ++j) v[j] = (float)C[(i + j) * 64 + lane];
            acc += ((v[0] + v[1]) + (v[2] + v[3])) + ((v[4] + v[5]) + (v[6] + v[7]));
            cn += 8;
            i += 8;
            continue;
        }
        const int b = batch[i];
        if (b != cur) {
            unsafeAtomicAdd(&pool[cur * 64 + lane], acc);
            if (lane == 0) unsafeAtomicAdd(&pool[64 * 64 + cur], (float)cn);
            cur = b;
            acc = 0.f;
            cn = 0;
        }
        acc += (float)C[i * 64 + lane];
        ++cn;
        ++i;
    }
    unsafeAtomicAdd(&pool[cur * 64 + lane], acc);
    if (lane == 0) unsafeAtomicAdd(&pool[64 * 64 + cur], (float)cn);
}

__global__ __launch_bounds__(256) void k_final(const float* __restrict__ pool,
                                               float* __restrict__ out) {
    const int i = blockIdx.x * 256 + threadIdx.x;
    if (i < 4096) {
        const int g = i >> 6;
        const float cnt = fmaxf(pool[64 * 64 + g], 1.0f);
        const float v = pool[i] / cnt;
        out[i] = 1.f / (1.f + expf(-v));
    }
}

// -------------------------------------------------------------- launch ----
extern "C" void kernel_launch(void* const* d_in, const int* in_sizes, int n_in,
                              void* d_out, int out_size, void* d_ws, size_t ws_size,
                              hipStream_t stream) {
    const float* x   = (const float*)d_in[0];
    const int*   ei  = (const int*)d_in[1];
    const float* ew  = (const float*)d_in[2];
    const int*   bat = (const int*)d_in[3];
    const float* W1  = (const float*)d_in[4];
    const float* b1  = (const float*)d_in[5];
    const float* g1  = (const float*)d_in[6];
    const float* bt1 = (const float*)d_in[7];
    const float* W2  = (const float*)d_in[8];
    const float* b2  = (const float*)d_in[9];
    const float* g2  = (const float*)d_in[10];
    const float* bt2 = (const float*)d_in[11];
    const int N = in_sizes[3];
    const int E = in_sizes[2];
    const int NBK = (N + 255) >> 8;          // 256-node buckets
    const int NBKp = (NBK + 2) & ~1;         // padded

    u64*    buck = (u64*)d_ws;                              // [E]
    u64*    srt  = buck + E;                                // [E]
    float2* ern  = (float2*)(srt + E);                      // [E]
    u32*    bhT  = (u32*)(ern + E);                         // [NBKp*NSB]
    u32*    baseT= bhT + (long)NBKp * NSB;                  // [NBKp*NSB]
    int*    barr = (int*)(baseT + (long)NBKp * NSB);        // [NBK+1] (+pad)
    unsigned char* Ah = (unsigned char*)(barr + NBK + 9);   // [N*128] fp8 h1/h2
    __bf16* Bh   = (__bf16*)(Ah + (long)N * 128);           // [N*128] bf16 ln1
    __bf16* Cb   = Bh + (long)N * 128;                      // [N*64] bf16 ln2
    float*  dinv = (float*)(Cb + (long)N * 64);             // [N]
    int*    cnt  = (int*)(dinv + N);                        // [N]
    int*    off  = cnt + N;                                 // [N]
    __bf16* Wt1  = (__bf16*)(off + N);                      // [128*256] blob
    __bf16* Wt2  = Wt1 + 128 * 256;                         // [64*128] blob
    float*  pool = (float*)(Wt2 + 64 * 128);                // [64*64+64]

    const int nbE = (E + 255) / 256;
    const int nbW = (int)(((long)N * 64 + 255) / 256);
    const int NBM = (N + 127) / 128;
    const int CH  = (E + NSB - 1) / NSB;

    hipMemsetAsync(pool, 0, (64 * 64 + 64) * sizeof(float), stream);
    k_wcvt<<<(256 * 128 + 128 * 64 + 255) / 256, 256, 0, stream>>>(W1, Wt1, W2, Wt2);

    // atomic-free CSR build (bucket sort, all atomics in LDS)
    k_bh<<<NSB, 256, 0, stream>>>(ei + E, bhT, E, CH, NBK);
    k_bscan<<<1, 256, 0, stream>>>(bhT, baseT, barr, NBK);
    k_bscat<<<NSB, 256, 0, stream>>>(ei, ew, baseT, buck, E, CH, NBK);
    k_bucket<<<NBK, 256, 0, stream>>>(buck, barr, srt, cnt, off, dinv, N);
    k_norm<<<nbE, 256, 0, stream>>>(srt, dinv, ern, E);

    // layer 1: GCNConv(256->128) + ReLU + LN
    k_mm1<<<NBM, 256, 0, stream>>>(x, Wt1, Ah, N);
    k_gat128<<<nbW, 256, 0, stream>>>(Ah, off, cnt, ern, dinv, b1, g1, bt1, Bh, N);

    // layer 2: GCNConv(128->64) + ReLU + LN
    k_mm2<<<NBM, 256, 0, stream>>>(Bh, Wt2, Ah, N);
    k_gat64<<<nbW, 256, 0, stream>>>(Ah, off, cnt, ern, dinv, b2, g2, bt2, Cb, N);

    // global mean pool + sigmoid
    const int chunk = (N + 1023) / 1024;
    k_pool<<<256, 256, 0, stream>>>(Cb, bat, pool, N, chunk);
    k_final<<<16, 256, 0, stream>>>(pool, (float*)d_out);
}

// Round 11
// 286.388 us; speedup vs baseline: 1.2599x; 1.2599x over previous
//
#include <hip/hip_runtime.h>
#include <cstdint>

#define EPSV 1e-5f

typedef __bf16 bf16x8 __attribute__((ext_vector_type(8)));
typedef __bf16 bf16x2 __attribute__((ext_vector_type(2)));
typedef float  f32x4  __attribute__((ext_vector_type(4)));
typedef unsigned long long u64;
typedef unsigned int u32;

#define NSB  512   // scatter/histogram blocks
#define BCAP 6144  // max edges per 256-node bucket (mean 4096, ~32 sigma guard)

// fp8 e4m3 (OCP) helpers — HW converts on gfx950.
__device__ __forceinline__ unsigned char f32_to_fp8(float x) {
    const int p = __builtin_amdgcn_cvt_pk_fp8_f32(x, x, 0, false);
    return (unsigned char)(p & 0xFF);
}

// ---------------------------------------------- bucket histogram (LDS) ----
__global__ __launch_bounds__(256) void k_bh(const int* __restrict__ eic,
                                            u32* __restrict__ bhT,
                                            int E, int CH, int NBK) {
    __shared__ int h[400];
    for (int i = threadIdx.x; i < NBK; i += 256) h[i] = 0;
    __syncthreads();
    const int lo = blockIdx.x * CH;
    const int hi = min(E, lo + CH);
    for (int e = lo + threadIdx.x; e < hi; e += 256)
        atomicAdd(&h[eic[e] >> 8], 1);
    __syncthreads();
    for (int b = threadIdx.x; b < NBK; b += 256)
        bhT[b * NSB + blockIdx.x] = (u32)h[b];
}

// ---------------- parallel scan stage 1: tot[b] = sum_j bhT[b][j] ---------
__global__ __launch_bounds__(256) void k_bsum(const u32* __restrict__ bhT,
                                              u32* __restrict__ tot) {
    __shared__ u32 ws[4];
    const int b = blockIdx.x;
    const u32* p = bhT + (long)b * NSB;
    u32 s = p[threadIdx.x] + p[threadIdx.x + 256];
#pragma unroll
    for (int o = 32; o >= 1; o >>= 1) s += __shfl_xor(s, o);
    if ((threadIdx.x & 63) == 0) ws[threadIdx.x >> 6] = s;
    __syncthreads();
    if (threadIdx.x == 0) tot[b] = ws[0] + ws[1] + ws[2] + ws[3];
}

// ---------------- stage 2: barr = exclusive scan of tot (1 small block) ---
__global__ __launch_bounds__(256) void k_bscan2(const u32* __restrict__ tot,
                                                int* __restrict__ barr, int NBK) {
    __shared__ int carry;
    __shared__ int wsum[4];
    if (threadIdx.x == 0) carry = 0;
    __syncthreads();
    const int lane = threadIdx.x & 63, w = threadIdx.x >> 6;
    for (int base = 0; base < NBK; base += 256) {
        const int i = base + threadIdx.x;
        const int v = (i < NBK) ? (int)tot[i] : 0;
        int s = v;
#pragma unroll
        for (int o = 1; o < 64; o <<= 1) {
            const int t = __shfl_up(s, o);
            if (lane >= o) s += t;
        }
        if (lane == 63) wsum[w] = s;
        __syncthreads();
        int add = carry;
        for (int k = 0; k < w; ++k) add += wsum[k];
        const int t4 = wsum[0] + wsum[1] + wsum[2] + wsum[3];
        if (i < NBK) barr[i] = add + s - v;
        __syncthreads();
        if (threadIdx.x == 0) {
            carry += t4;
            if (base + 256 >= NBK) barr[NBK] = carry;
        }
        __syncthreads();
    }
}

// -------- stage 3: baseT[b][j] = barr[b] + prefix_j(bhT[b][·]) ------------
__global__ __launch_bounds__(256) void k_bbase(const u32* __restrict__ bhT,
                                               const int* __restrict__ barr,
                                               u32* __restrict__ baseT) {
    __shared__ u32 wsum[4];
    const int b = blockIdx.x;
    const u32* p = bhT + (long)b * NSB;
    u32* q = baseT + (long)b * NSB;
    const int lane = threadIdx.x & 63, w = threadIdx.x >> 6;
    const u32 v0 = p[2 * threadIdx.x];
    const u32 v1 = p[2 * threadIdx.x + 1];
    const u32 pv = v0 + v1;
    u32 s = pv;
#pragma unroll
    for (int o = 1; o < 64; o <<= 1) {
        const u32 t = __shfl_up(s, o);
        if (lane >= o) s += t;
    }
    if (lane == 63) wsum[w] = s;
    __syncthreads();
    u32 add = (u32)barr[b];
    for (int k = 0; k < w; ++k) add += wsum[k];
    const u32 excl = add + s - pv;
    q[2 * threadIdx.x] = excl;
    q[2 * threadIdx.x + 1] = excl + v0;
}

// ------------------- scatter edges into buckets (plain stores, LDS rank) --
// pack: (c&255)<<33 | r<<16 | w16   (r<2^17, w16 = round(w*65535))
__global__ __launch_bounds__(256) void k_bscat(const int* __restrict__ ei,
                                               const float* __restrict__ ew,
                                               const u32* __restrict__ baseT,
                                               u64* __restrict__ buck,
                                               int E, int CH, int NBK) {
    __shared__ u32 base[400];
    __shared__ u32 cur[400];
    for (int i = threadIdx.x; i < NBK; i += 256) {
        base[i] = baseT[i * NSB + blockIdx.x];
        cur[i] = 0;
    }
    __syncthreads();
    const int lo = blockIdx.x * CH;
    const int hi = min(E, lo + CH);
    for (int e = lo + threadIdx.x; e < hi; e += 256) {
        const int c = ei[E + e];
        const int r = ei[e];
        const int b = c >> 8;
        const u32 rk = atomicAdd(&cur[b], 1u);
        const u32 w16 = (u32)(ew[e] * 65535.0f + 0.5f);
        buck[base[b] + rk] = ((u64)(c & 255) << 33) | ((u64)r << 16) | (u64)w16;
    }
}

// ------ per-bucket: counts, deg, node-sort; emits cnt/off/dinv + srt ------
__global__ __launch_bounds__(256) void k_bucket(const u64* __restrict__ buck,
                                                const int* __restrict__ barr,
                                                u64* __restrict__ srt,
                                                int* __restrict__ cnt,
                                                int* __restrict__ off,
                                                float* __restrict__ dinv, int N) {
    __shared__ u64 arr[BCAP];
    __shared__ int lc[256];
    __shared__ float ldeg[256];
    __shared__ int loff[256];
    __shared__ int wsum[4];
    const int b = blockIdx.x;
    const int e0 = barr[b];
    const int nb = min(barr[b + 1] - e0, BCAP);

    lc[threadIdx.x] = 0;
    ldeg[threadIdx.x] = 0.f;
    __syncthreads();

    for (int i = threadIdx.x; i < nb; i += 256) {
        const u64 v = buck[e0 + i];
        arr[i] = v;
        const int cl = (int)(v >> 33) & 255;
        atomicAdd(&lc[cl], 1);
        atomicAdd(&ldeg[cl], (float)(u32)(v & 0xFFFF) * (1.0f / 65535.0f));
    }
    __syncthreads();

    // exclusive scan of lc -> loff
    const int lane = threadIdx.x & 63, w = threadIdx.x >> 6;
    const int vv = lc[threadIdx.x];
    int s = vv;
#pragma unroll
    for (int o = 1; o < 64; o <<= 1) {
        const int t = __shfl_up(s, o);
        if (lane >= o) s += t;
    }
    if (lane == 63) wsum[w] = s;
    __syncthreads();
    int add = 0;
    for (int k = 0; k < w; ++k) add += wsum[k];
    loff[threadIdx.x] = add + s - vv;
    __syncthreads();

    const int c = b * 256 + threadIdx.x;
    if (c < N) {
        cnt[c] = vv;
        off[c] = e0 + loff[threadIdx.x];
        dinv[c] = rsqrtf(1.0f + ldeg[threadIdx.x]);
    }

    __syncthreads();
    lc[threadIdx.x] = 0;
    __syncthreads();
    for (int i = threadIdx.x; i < nb; i += 256) {
        const u64 v = arr[i];
        const int cl = (int)(v >> 33) & 255;
        const int rk = atomicAdd(&lc[cl], 1);
        srt[e0 + loff[cl] + rk] =
            ((u64)(b * 256 + cl) << 33) | (v & 0x1FFFFFFFFull);
    }
}

// ------------------------- norms: ern[p] = (r, dinv[r]*w*dinv[c]) ---------
__global__ __launch_bounds__(256) void k_norm(const u64* __restrict__ srt,
                                              const float* __restrict__ dinv,
                                              float2* __restrict__ ern, int E) {
    const int p = blockIdx.x * 256 + threadIdx.x;
    if (p >= E) return;
    const u64 v = srt[p];
    const int c = (int)(v >> 33);
    const int r = (int)((v >> 16) & 0x1FFFF);
    const float w = (float)(u32)(v & 0xFFFF) * (1.0f / 65535.0f);
    ern[p] = make_float2(__int_as_float(r), dinv[r] * w * dinv[c]);
}

// ----------------------------------------------------- W transpose+cvt ----
// Blob layout: WtB[k/8][c][8] bf16.
__global__ __launch_bounds__(256) void k_wcvt(const float* __restrict__ W1,
                                              __bf16* __restrict__ Wt1,
                                              const float* __restrict__ W2,
                                              __bf16* __restrict__ Wt2) {
    const int idx = blockIdx.x * 256 + threadIdx.x;
    if (idx < 256 * 128) {                       // K=256, NOUT=128
        const int k = idx >> 7, c = idx & 127;
        Wt1[(((k >> 3) << 7) + c) * 8 + (k & 7)] = (__bf16)W1[idx];
    } else if (idx < 256 * 128 + 128 * 64) {     // K=128, NOUT=64
        const int j = idx - 256 * 128;
        const int k = j >> 6, c = j & 63;
        Wt2[(((k >> 3) << 6) + c) * 8 + (k & 7)] = (__bf16)W2[j];
    }
}

// ----------------------------------------------------------- MFMA GEMM ----
template <int K, int NOUT, bool ABF16>
__device__ __forceinline__ void mm_body(int bid, int tid, const void* __restrict__ Xv,
                                        const __bf16* __restrict__ WtB,
                                        unsigned char* __restrict__ H, int N) {
    constexpr int NCB = NOUT / 16;
    constexpr int NKB = K / 32;
    const int w = tid >> 6, l = tid & 63;
    const int r0 = l & 15, kq = l >> 4;
    const long tb0 = (long)bid * 128 + w * 32;
    const long ar0 = (tb0 + r0) < N ? (tb0 + r0) : (long)N - 1;
    const long ar1 = (tb0 + 16 + r0) < N ? (tb0 + 16 + r0) : (long)N - 1;

    f32x4 acc[2][NCB];
#pragma unroll
    for (int rf = 0; rf < 2; ++rf)
#pragma unroll
        for (int cb = 0; cb < NCB; ++cb) acc[rf][cb] = (f32x4){0.f, 0.f, 0.f, 0.f};

#define LDA(kb, a0, a1)                                                          \
    {                                                                            \
        const int koff = (kb) * 32 + kq * 8;                                     \
        if constexpr (ABF16) {                                                   \
            a0 = *reinterpret_cast<const bf16x8*>((const __bf16*)Xv + ar0 * K + koff); \
            a1 = *reinterpret_cast<const bf16x8*>((const __bf16*)Xv + ar1 * K + koff); \
        } else {                                                                 \
            const float* p0 = (const float*)Xv + ar0 * K + koff;                 \
            const float* p1 = (const float*)Xv + ar1 * K + koff;                 \
            const float4 u0 = *reinterpret_cast<const float4*>(p0);              \
            const float4 u1 = *reinterpret_cast<const float4*>(p0 + 4);          \
            const float4 u2 = *reinterpret_cast<const float4*>(p1);              \
            const float4 u3 = *reinterpret_cast<const float4*>(p1 + 4);          \
            a0[0] = (__bf16)u0.x; a0[1] = (__bf16)u0.y; a0[2] = (__bf16)u0.z;    \
            a0[3] = (__bf16)u0.w; a0[4] = (__bf16)u1.x; a0[5] = (__bf16)u1.y;    \
            a0[6] = (__bf16)u1.z; a0[7] = (__bf16)u1.w;                          \
            a1[0] = (__bf16)u2.x; a1[1] = (__bf16)u2.y; a1[2] = (__bf16)u2.z;    \
            a1[3] = (__bf16)u2.w; a1[4] = (__bf16)u3.x; a1[5] = (__bf16)u3.y;    \
            a1[6] = (__bf16)u3.z; a1[7] = (__bf16)u3.w;                          \
        }                                                                        \
    }

#define LDB(kb, b)                                                               \
    {                                                                            \
        const __bf16* bp = WtB + (long)(((kb) * 4 + kq) * NOUT + r0) * 8;        \
        _Pragma("unroll") for (int cb = 0; cb < NCB; ++cb)                       \
            b[cb] = *reinterpret_cast<const bf16x8*>(bp + cb * 128);             \
    }

    bf16x8 aC0, aC1, aN0, aN1;
    bf16x8 bC[NCB], bN[NCB];
    LDA(0, aC0, aC1);
    LDB(0, bC);
#pragma unroll
    for (int kb = 0; kb < NKB; ++kb) {
        if (kb + 1 < NKB) {
            LDA(kb + 1, aN0, aN1);
            LDB(kb + 1, bN);
        }
#pragma unroll
        for (int cb = 0; cb < NCB; ++cb) {
            acc[0][cb] = __builtin_amdgcn_mfma_f32_16x16x32_bf16(aC0, bC[cb], acc[0][cb], 0, 0, 0);
            acc[1][cb] = __builtin_amdgcn_mfma_f32_16x16x32_bf16(aC1, bC[cb], acc[1][cb], 0, 0, 0);
        }
        aC0 = aN0; aC1 = aN1;
#pragma unroll
        for (int cb = 0; cb < NCB; ++cb) bC[cb] = bN[cb];
    }
#undef LDA
#undef LDB

    const int orow = kq * 4;
#pragma unroll
    for (int rf = 0; rf < 2; ++rf)
#pragma unroll
        for (int cb = 0; cb < NCB; ++cb)
#pragma unroll
            for (int r = 0; r < 4; ++r) {
                const long gr = tb0 + rf * 16 + orow + r;
                if (gr < N) H[gr * NOUT + cb * 16 + r0] = f32_to_fp8(acc[rf][cb][r]);
            }
}

__global__ __launch_bounds__(256) void k_mm1(const float* __restrict__ X,
                                             const __bf16* __restrict__ Wt1,
                                             unsigned char* __restrict__ H, int N) {
    mm_body<256, 128, false>(blockIdx.x, threadIdx.x, X, Wt1, H, N);
}

__global__ __launch_bounds__(256) void k_mm2(const __bf16* __restrict__ X,
                                             const __bf16* __restrict__ Wt2,
                                             unsigned char* __restrict__ H, int N) {
    mm_body<128, 64, true>(blockIdx.x, threadIdx.x, X, Wt2, H, N);
}

// --------------------------------- gather + bias + ReLU + LayerNorm -------
__global__ __launch_bounds__(256) void k_gat128(const unsigned char* __restrict__ H,
                                                const int* __restrict__ off,
                                                const int* __restrict__ cnt,
                                                const float2* __restrict__ ern,
                                                const float* __restrict__ dinv,
                                                const float* __restrict__ bias,
                                                const float* __restrict__ gm,
                                                const float* __restrict__ bt,
                                                __bf16* __restrict__ Out, int N) {
    const long wv = ((long)blockIdx.x * 256 + threadIdx.x) >> 6;
    const int lane = threadIdx.x & 63;
    if (wv >= N) return;
    const int s = off[wv];
    const int n = cnt[wv];
    const float d = dinv[wv];
    const unsigned short* Hp = reinterpret_cast<const unsigned short*>(H);

    const unsigned int h0 = Hp[wv * 64 + lane];
    float ax = __builtin_amdgcn_cvt_f32_fp8(h0, 0) * d * d;
    float ay = __builtin_amdgcn_cvt_f32_fp8(h0, 1) * d * d;

    int e = 0;
    for (; e + 8 <= n; e += 8) {
        float2 q[8];
#pragma unroll
        for (int j = 0; j < 8; ++j) q[j] = ern[s + e + j];
        unsigned int u[8];
#pragma unroll
        for (int j = 0; j < 8; ++j)
            u[j] = Hp[(long)__float_as_int(q[j].x) * 64 + lane];
#pragma unroll
        for (int j = 0; j < 8; ++j) {
            ax = fmaf(q[j].y, __builtin_amdgcn_cvt_f32_fp8(u[j], 0), ax);
            ay = fmaf(q[j].y, __builtin_amdgcn_cvt_f32_fp8(u[j], 1), ay);
        }
    }
    for (; e < n; ++e) {
        const float2 q = ern[s + e];
        const unsigned int u = Hp[(long)__float_as_int(q.x) * 64 + lane];
        ax = fmaf(q.y, __builtin_amdgcn_cvt_f32_fp8(u, 0), ax);
        ay = fmaf(q.y, __builtin_amdgcn_cvt_f32_fp8(u, 1), ay);
    }

    const float ux = fmaxf(ax + bias[2 * lane], 0.f);
    const float uy = fmaxf(ay + bias[2 * lane + 1], 0.f);
    float s1 = ux + uy, s2 = ux * ux + uy * uy;
#pragma unroll
    for (int o = 32; o >= 1; o >>= 1) {
        s1 += __shfl_xor(s1, o);
        s2 += __shfl_xor(s2, o);
    }
    const float mu = s1 * (1.f / 128.f);
    const float var = s2 * (1.f / 128.f) - mu * mu;
    const float rs = rsqrtf(var + EPSV);
    bf16x2 ob;
    ob[0] = (__bf16)((ux - mu) * rs * gm[2 * lane] + bt[2 * lane]);
    ob[1] = (__bf16)((uy - mu) * rs * gm[2 * lane + 1] + bt[2 * lane + 1]);
    reinterpret_cast<bf16x2*>(Out)[wv * 64 + lane] = ob;
}

__global__ __launch_bounds__(256) void k_gat64(const unsigned char* __restrict__ H,
                                               const int* __restrict__ off,
                                               const int* __restrict__ cnt,
                                               const float2* __restrict__ ern,
                                               const float* __restrict__ dinv,
                                               const float* __restrict__ bias,
                                               const float* __restrict__ gm,
                                               const float* __restrict__ bt,
                                               __bf16* __restrict__ Out, int N) {
    const long wv = ((long)blockIdx.x * 256 + threadIdx.x) >> 6;
    const int lane = threadIdx.x & 63;
    if (wv >= N) return;
    const int s = off[wv];
    const int n = cnt[wv];
    const float d = dinv[wv];

    float acc = __builtin_amdgcn_cvt_f32_fp8((unsigned int)H[wv * 64 + lane], 0) * d * d;
    int e = 0;
    for (; e + 8 <= n; e += 8) {
        float2 q[8];
#pragma unroll
        for (int j = 0; j < 8; ++j) q[j] = ern[s + e + j];
        unsigned int u[8];
#pragma unroll
        for (int j = 0; j < 8; ++j)
            u[j] = H[(long)__float_as_int(q[j].x) * 64 + lane];
#pragma unroll
        for (int j = 0; j < 8; ++j)
            acc = fmaf(q[j].y, __builtin_amdgcn_cvt_f32_fp8(u[j], 0), acc);
    }
    for (; e < n; ++e) {
        const float2 q = ern[s + e];
        const unsigned int u = H[(long)__float_as_int(q.x) * 64 + lane];
        acc = fmaf(q.y, __builtin_amdgcn_cvt_f32_fp8(u, 0), acc);
    }

    const float u = fmaxf(acc + bias[lane], 0.f);
    float s1 = u, s2 = u * u;
#pragma unroll
    for (int o = 32; o >= 1; o >>= 1) {
        s1 += __shfl_xor(s1, o);
        s2 += __shfl_xor(s2, o);
    }
    const float mu = s1 * (1.f / 64.f);
    const float var = s2 * (1.f / 64.f) - mu * mu;
    const float rs = rsqrtf(var + EPSV);
    Out[wv * 64 + lane] = (__bf16)((u - mu) * rs * gm[lane] + bt[lane]);
}

// ---------------------------------------------------------------- pool ----
__global__ __launch_bounds__(256) void k_pool(const __bf16* __restrict__ C,
                                              const int* __restrict__ batch,
                                              float* __restrict__ pool,
                                              int N, int chunk) {
    const int wg = blockIdx.x * 4 + (threadIdx.x >> 6);
    const int lane = threadIdx.x & 63;
    long i = (long)wg * chunk;
    const long end = (i + chunk < (long)N) ? i + chunk : (long)N;
    if (i >= end) return;

    int cur = batch[i];
    float acc = 0.f;
    int cn = 0;
    while (i < end) {
        if (i + 8 <= end && batch[i + 7] == cur) {
            float v[8];
#pragma unroll
            for (int j = 0; j < 8; ++j) v[j] = (float)C[(i + j) * 64 + lane];
            acc += ((v[0] + v[1]) + (v[2] + v[3])) + ((v[4] + v[5]) + (v[6] + v[7]));
            cn += 8;
            i += 8;
            continue;
        }
        const int b = batch[i];
        if (b != cur) {
            unsafeAtomicAdd(&pool[cur * 64 + lane], acc);
            if (lane == 0) unsafeAtomicAdd(&pool[64 * 64 + cur], (float)cn);
            cur = b;
            acc = 0.f;
            cn = 0;
        }
        acc += (float)C[i * 64 + lane];
        ++cn;
        ++i;
    }
    unsafeAtomicAdd(&pool[cur * 64 + lane], acc);
    if (lane == 0) unsafeAtomicAdd(&pool[64 * 64 + cur], (float)cn);
}

__global__ __launch_bounds__(256) void k_final(const float* __restrict__ pool,
                                               float* __restrict__ out) {
    const int i = blockIdx.x * 256 + threadIdx.x;
    if (i < 4096) {
        const int g = i >> 6;
        const float cnt = fmaxf(pool[64 * 64 + g], 1.0f);
        const float v = pool[i] / cnt;
        out[i] = 1.f / (1.f + expf(-v));
    }
}

// -------------------------------------------------------------- launch ----
extern "C" void kernel_launch(void* const* d_in, const int* in_sizes, int n_in,
                              void* d_out, int out_size, void* d_ws, size_t ws_size,
                              hipStream_t stream) {
    const float* x   = (const float*)d_in[0];
    const int*   ei  = (const int*)d_in[1];
    const float* ew  = (const float*)d_in[2];
    const int*   bat = (const int*)d_in[3];
    const float* W1  = (const float*)d_in[4];
    const float* b1  = (const float*)d_in[5];
    const float* g1  = (const float*)d_in[6];
    const float* bt1 = (const float*)d_in[7];
    const float* W2  = (const float*)d_in[8];
    const float* b2  = (const float*)d_in[9];
    const float* g2  = (const float*)d_in[10];
    const float* bt2 = (const float*)d_in[11];
    const int N = in_sizes[3];
    const int E = in_sizes[2];
    const int NBK = (N + 255) >> 8;          // 256-node buckets
    const int NBKp = (NBK + 2) & ~1;         // padded

    u64*    buck = (u64*)d_ws;                              // [E]
    u64*    srt  = buck + E;                                // [E]
    float2* ern  = (float2*)(srt + E);                      // [E]
    u32*    bhT  = (u32*)(ern + E);                         // [NBKp*NSB]
    u32*    baseT= bhT + (long)NBKp * NSB;                  // [NBKp*NSB]
    u32*    tot  = baseT + (long)NBKp * NSB;                // [NBKp]
    int*    barr = (int*)(tot + NBKp);                      // [NBK+1] (+pad)
    unsigned char* Ah = (unsigned char*)(barr + NBK + 9);   // [N*128] fp8 h1/h2
    __bf16* Bh   = (__bf16*)(Ah + (long)N * 128);           // [N*128] bf16 ln1
    __bf16* Cb   = Bh + (long)N * 128;                      // [N*64] bf16 ln2
    float*  dinv = (float*)(Cb + (long)N * 64);             // [N]
    int*    cnt  = (int*)(dinv + N);                        // [N]
    int*    off  = cnt + N;                                 // [N]
    __bf16* Wt1  = (__bf16*)(off + N);                      // [128*256] blob
    __bf16* Wt2  = Wt1 + 128 * 256;                         // [64*128] blob
    float*  pool = (float*)(Wt2 + 64 * 128);                // [64*64+64]

    const int nbE = (E + 255) / 256;
    const int nbW = (int)(((long)N * 64 + 255) / 256);
    const int NBM = (N + 127) / 128;
    const int CH  = (E + NSB - 1) / NSB;

    hipMemsetAsync(pool, 0, (64 * 64 + 64) * sizeof(float), stream);
    k_wcvt<<<(256 * 128 + 128 * 64 + 255) / 256, 256, 0, stream>>>(W1, Wt1, W2, Wt2);

    // atomic-free CSR build (bucket sort, all atomics in LDS)
    k_bh<<<NSB, 256, 0, stream>>>(ei + E, bhT, E, CH, NBK);
    k_bsum<<<NBK, 256, 0, stream>>>(bhT, tot);
    k_bscan2<<<1, 256, 0, stream>>>(tot, barr, NBK);
    k_bbase<<<NBK, 256, 0, stream>>>(bhT, barr, baseT);
    k_bscat<<<NSB, 256, 0, stream>>>(ei, ew, baseT, buck, E, CH, NBK);
    k_bucket<<<NBK, 256, 0, stream>>>(buck, barr, srt, cnt, off, dinv, N);
    k_norm<<<nbE, 256, 0, stream>>>(srt, dinv, ern, E);

    // layer 1: GCNConv(256->128) + ReLU + LN
    k_mm1<<<NBM, 256, 0, stream>>>(x, Wt1, Ah, N);
    k_gat128<<<nbW, 256, 0, stream>>>(Ah, off, cnt, ern, dinv, b1, g1, bt1, Bh, N);

    // layer 2: GCNConv(128->64) + ReLU + LN
    k_mm2<<<NBM, 256, 0, stream>>>(Bh, Wt2, Ah, N);
    k_gat64<<<nbW, 256, 0, stream>>>(Ah, off, cnt, ern, dinv, b2, g2, bt2, Cb, N);

    // global mean pool + sigmoid
    const int chunk = (N + 1023) / 1024;
    k_pool<<<256, 256, 0, stream>>>(Cb, bat, pool, N, chunk);
    k_final<<<16, 256, 0, stream>>>(pool, (float*)d_out);
}